// Round 10
// baseline (61.058 us; speedup 1.0000x reference)
//
#include <hip/hip_runtime.h>
#include <math.h>

#define NH 16
#define TT 1024
#define HD 64
#define NE 1024

typedef unsigned int u32;
typedef unsigned short u16;
typedef __bf16 bf16x8 __attribute__((ext_vector_type(8)));
typedef float f32x4 __attribute__((ext_vector_type(4)));

__device__ inline u16 f2bf(float f) {
  u32 u = __builtin_bit_cast(u32, f);
  u32 r = (u + 0x7fffu + ((u >> 16) & 1u)) >> 16;
  return (u16)r;
}
__device__ inline u32 pk2bf(float lo, float hi) {
  return (u32)f2bf(lo) | ((u32)f2bf(hi) << 16);
}
__device__ inline float bf2f(u16 h) {
  return __builtin_bit_cast(float, (u32)h << 16);
}
__device__ inline void gload16(const void* g, void* l) {
  __builtin_amdgcn_global_load_lds((const __attribute__((address_space(1))) void*)g,
                                   (__attribute__((address_space(3))) void*)l, 16, 0, 0);
}
__device__ inline u16 h16(uint4 v, int e) {
  u32 w = ((const u32*)&v)[e >> 1];
  return (e & 1) ? (u16)(w >> 16) : (u16)(w & 0xffffu);
}

// Fused prep: blocks [0,1024) convert x -> bf16; [1024,2048) transpose weights.
__global__ __launch_bounds__(256) void prep(const float* __restrict__ x,
                                            const float* __restrict__ Wqkv,
                                            const float* __restrict__ Wout,
                                            u16* __restrict__ xb,
                                            u16* __restrict__ WqkvT,
                                            u16* __restrict__ WoutT) {
  __shared__ float tile[64][65];
  const int tid = threadIdx.x;
  const int bx = blockIdx.x;
  if (bx < 1024) {
    int i = bx * 256 + tid;
    float4 f = ((const float4*)x)[i];
    ushort4 o = {f2bf(f.x), f2bf(f.y), f2bf(f.z), f2bf(f.w)};
    ((ushort4*)xb)[i] = o;
    return;
  }
  int b = bx - 1024;
  int nb = b & 63, kb = b >> 6;
  const float* W; u16* WT; int N, n0;
  if (nb < 48) { W = Wqkv; WT = WqkvT; N = 3 * NE; n0 = nb * 64; }
  else         { W = Wout; WT = WoutT; N = NE;     n0 = (nb - 48) * 64; }
  const int k0 = kb * 64;
#pragma unroll
  for (int it = 0; it < 16; ++it) {
    int idx = it * 256 + tid;
    int r = idx >> 6, c = idx & 63;
    tile[r][c] = W[(size_t)(k0 + r) * N + n0 + c];
  }
  __syncthreads();
#pragma unroll
  for (int it = 0; it < 16; ++it) {
    int idx = it * 256 + tid;
    int nn = idx >> 6, kk = idx & 63;
    WT[(size_t)(n0 + nn) * NE + k0 + kk] = f2bf(tile[kk][nn]);
  }
}

// Stage R rows x 64 k of bf16 into LDS, chunk-swizzled: slot(r,kg)=kg^(r&7).
template<int R>
__device__ __forceinline__ void stage_rows(const u16* __restrict__ G, int ldk,
                                           u16* L, int tid) {
#pragma unroll
  for (int it = 0; it < R / 32; ++it) {
    int idx = it * 256 + tid;
    int r = idx >> 3, kg = idx & 7;
    gload16(G + (size_t)r * ldk + ((kg ^ (r & 7)) << 3), L + (idx << 3));
  }
}

// bf16 MFMA GEMM: 128 x NT tile, BK=64, 4 waves (2x2), dbuf, swizzled LDS.
// Writes f32 split-K partials: C[sk*M*N + t*N + n].  (R5-verified structure.)
template<int SPLITK, int NT>
__global__ __launch_bounds__(256) void gemm_bt(const u16* __restrict__ A,
                                               const u16* __restrict__ Bt,
                                               float* __restrict__ C,
                                               int M, int N, int K) {
  __shared__ u16 As[2][128 * 64];
  __shared__ u16 Bs[2][NT * 64];
  const int tid = threadIdx.x;
  const int lane = tid & 63;
  const int wv = tid >> 6;
  const int wm = wv >> 1, wn = wv & 1;
  const int row0 = blockIdx.y * 128;
  const int col0 = blockIdx.x * NT;
  const int sk = blockIdx.z;
  const int Klen = K / SPLITK;
  const int nsteps = Klen >> 6;
  constexpr int NI = NT / 32;

  const u16* Ab = A + (size_t)row0 * K + sk * Klen;
  const u16* Bb = Bt + (size_t)col0 * K + sk * Klen;

  f32x4 acc[4][NI] = {};

  stage_rows<128>(Ab, K, As[0], tid);
  stage_rows<NT>(Bb, K, Bs[0], tid);
  __syncthreads();

  int buf = 0;
  for (int ks = 0; ks < nsteps; ++ks) {
    if (ks + 1 < nsteps) {
      stage_rows<128>(Ab + (ks + 1) * 64, K, As[buf ^ 1], tid);
      stage_rows<NT>(Bb + (ks + 1) * 64, K, Bs[buf ^ 1], tid);
    }
#pragma unroll
    for (int half = 0; half < 2; ++half) {
      const int kk = half * 32;
      bf16x8 af[4], bfr[NI];
#pragma unroll
      for (int mi = 0; mi < 4; ++mi) {
        int r = wm * 64 + mi * 16 + (lane & 15);
        int c = (kk >> 3) + (lane >> 4);
        af[mi] = *(const bf16x8*)&As[buf][(r * 8 + (c ^ (r & 7))) * 8];
      }
#pragma unroll
      for (int ni = 0; ni < NI; ++ni) {
        int r = wn * (NT / 2) + ni * 16 + (lane & 15);
        int c = (kk >> 3) + (lane >> 4);
        bfr[ni] = *(const bf16x8*)&Bs[buf][(r * 8 + (c ^ (r & 7))) * 8];
      }
#pragma unroll
      for (int mi = 0; mi < 4; ++mi)
#pragma unroll
        for (int ni = 0; ni < NI; ++ni)
          acc[mi][ni] = __builtin_amdgcn_mfma_f32_16x16x32_bf16(af[mi], bfr[ni], acc[mi][ni], 0, 0, 0);
    }
    __syncthreads();
    buf ^= 1;
  }

  const int rbase = row0 + wm * 64 + (lane >> 4) * 4;
  const int cbase = col0 + wn * (NT / 2) + (lane & 15);
  float* Cp = C + (size_t)sk * M * N;
#pragma unroll
  for (int mi = 0; mi < 4; ++mi)
#pragma unroll
    for (int ni = 0; ni < NI; ++ni)
#pragma unroll
      for (int r = 0; r < 4; ++r)
        Cp[(size_t)(rbase + mi * 16 + r) * N + cbase + ni * 16] = acc[mi][ni][r];
}

__global__ __launch_bounds__(256) void reduce_out(const float* __restrict__ P,
                                                  float* __restrict__ out) {
  int i = blockIdx.x * 256 + threadIdx.x;
  f32x4 a = ((const f32x4*)P)[i];
  a += ((const f32x4*)(P + (size_t)TT * NE))[i];
  a += ((const f32x4*)(P + 2 * (size_t)TT * NE))[i];
  a += ((const f32x4*)(P + 3 * (size_t)TT * NE))[i];
  ((f32x4*)out)[i] = a;
}

// Tiled gathered attention, MFMA QK^T + MFMA PV. Reads qkv DIRECTLY from the
// two f32 split-K partial slices of gemm1 (add+cvt fused into staging) --
// no reduce_qkv kernel, no qkvb buffer.
// One block per (h, 16-row tile); <=128 superset columns (80 window,
// 16 landmarks, 32 prev/next dedup'd).
__global__ __launch_bounds__(256) void attn6(const float* __restrict__ Pg,
                                             const int* __restrict__ nidx,
                                             u16* __restrict__ y, int D) {
  __shared__ __align__(16) u16 Qs[16 * 64];     // 2KB
  __shared__ __align__(16) u16 Ks[128 * 64];    // 16KB; S f32[16][132] overlays; P bf16 at +8448
  __shared__ __align__(16) u16 Vt[64 * 128];    // 16KB, octet-swizzled [d][k]
  __shared__ int pn_l[32];
  __shared__ int colj[128];
  __shared__ float rinv[16];
  float* S = (float*)Ks;
  u16* P = (u16*)((char*)Ks + 8448);

  const int tid = threadIdx.x;
  const int lane = tid & 63;
  const int wv = tid >> 6;
  const int h = blockIdx.y;
  const int t0 = blockIdx.x * 16;

  const float* Pg2 = Pg + (size_t)TT * 3 * NE;   // second split-K partial
  const int qoff = h * HD;                        // q col base in [t][3072]
  const int koff = NE + h * HD;
  const int voff = 2 * NE + h * HD;

  if (tid < 32) pn_l[tid] = nidx[((size_t)h * TT + t0 + (tid >> 1)) * D + (tid & 1)];

  // Q stage: sum 2 partials, cvt, pack -> same swizzled LDS slots as before
  if (tid < 128) {
    int row = tid >> 3, slot = tid & 7, ch = slot ^ (row & 7);
    const float* s1 = Pg  + (size_t)(t0 + row) * (3 * NE) + qoff + ch * 8;
    const float* s2 = Pg2 + (size_t)(t0 + row) * (3 * NE) + qoff + ch * 8;
    float4 a0 = *(const float4*)s1, a1 = *(const float4*)(s1 + 4);
    float4 b0 = *(const float4*)s2, b1 = *(const float4*)(s2 + 4);
    uint4 pk = {pk2bf(a0.x + b0.x, a0.y + b0.y), pk2bf(a0.z + b0.z, a0.w + b0.w),
                pk2bf(a1.x + b1.x, a1.y + b1.y), pk2bf(a1.z + b1.z, a1.w + b1.w)};
    *(uint4*)&Qs[tid * 8] = pk;
  }
  __syncthreads();

  if (tid < 128) {
    int c = tid, j;
    if (c < 80) {
      j = t0 - 64 + c;
      if (j < 0) j = -1;
    } else if (c < 96) {
      j = (c - 80) * 64;
      if (j >= t0 - 64) j = -1;
    } else {
      int s = c - 96;
      j = pn_l[s];
      bool keep = (j < t0 - 64) && ((j & 63) != 0);
      if (keep)
        for (int s2 = 0; s2 < s; ++s2)
          if (pn_l[s2] == j) { keep = false; break; }
      if (!keep) j = -1;
    }
    colj[c] = j;
  }
  __syncthreads();

  // K -> LDS (chunk-swizzled, add+cvt); V -> registers (4 consecutive cols x d-octet)
#pragma unroll
  for (int it = 0; it < 4; ++it) {
    int idx = it * 256 + tid;
    int col = idx >> 3, slot = idx & 7, ch = slot ^ (col & 7);
    int j = colj[col]; if (j < 0) j = 0;
    const float* s1 = Pg  + (size_t)j * (3 * NE) + koff + ch * 8;
    const float* s2 = Pg2 + (size_t)j * (3 * NE) + koff + ch * 8;
    float4 a0 = *(const float4*)s1, a1 = *(const float4*)(s1 + 4);
    float4 b0 = *(const float4*)s2, b1 = *(const float4*)(s2 + 4);
    uint4 pk = {pk2bf(a0.x + b0.x, a0.y + b0.y), pk2bf(a0.z + b0.z, a0.w + b0.w),
                pk2bf(a1.x + b1.x, a1.y + b1.y), pk2bf(a1.z + b1.z, a1.w + b1.w)};
    *(uint4*)&Ks[idx * 8] = pk;
  }
  const int d0 = (tid & 7) * 8;
  const int cq = tid >> 3;          // col-quad 0..31 -> cols cq*4..+3
  uint4 vreg[4];
#pragma unroll
  for (int it = 0; it < 4; ++it) {
    int col = cq * 4 + it;
    int j = colj[col]; if (j < 0) j = 0;
    const float* s1 = Pg  + (size_t)j * (3 * NE) + voff + d0;
    const float* s2 = Pg2 + (size_t)j * (3 * NE) + voff + d0;
    float4 a0 = *(const float4*)s1, a1 = *(const float4*)(s1 + 4);
    float4 b0 = *(const float4*)s2, b1 = *(const float4*)(s2 + 4);
    vreg[it].x = pk2bf(a0.x + b0.x, a0.y + b0.y);
    vreg[it].y = pk2bf(a0.z + b0.z, a0.w + b0.w);
    vreg[it].z = pk2bf(a1.x + b1.x, a1.y + b1.y);
    vreg[it].w = pk2bf(a1.z + b1.z, a1.w + b1.w);
  }
  __syncthreads();

  // QK^T: wave wv owns col-tiles 2wv, 2wv+1
  f32x4 sc[2] = {};
  bf16x8 af[2];
#pragma unroll
  for (int half = 0; half < 2; ++half) {
    int row = lane & 15;
    int chunk = 4 * half + (lane >> 4);
    af[half] = *(const bf16x8*)&Qs[(row * 8 + (chunk ^ (row & 7))) * 8];
  }
#pragma unroll
  for (int p = 0; p < 2; ++p) {
    int col = 16 * (2 * wv + p) + (lane & 15);
#pragma unroll
    for (int half = 0; half < 2; ++half) {
      int chunk = 4 * half + (lane >> 4);
      bf16x8 bfv = *(const bf16x8*)&Ks[(col * 8 + (chunk ^ (col & 7))) * 8];
      sc[p] = __builtin_amdgcn_mfma_f32_16x16x32_bf16(af[half], bfv, sc[p], 0, 0, 0);
    }
  }
  __syncthreads();   // done reading Ks; S may overlay

  // mask + S write
#pragma unroll
  for (int p = 0; p < 2; ++p) {
    int col = 16 * (2 * wv + p) + (lane & 15);
    int j = colj[col];
#pragma unroll
    for (int r = 0; r < 4; ++r) {
      int row = (lane >> 4) * 4 + r;
      int i = t0 + row;
      int p0 = pn_l[2 * row], p1 = pn_l[2 * row + 1];
      bool m;
      if (col < 80)      m = (j >= 0) && (j <= i) &&
                             ((i - j) <= 64 || (j & 63) == 0 || j == p0 || j == p1);
      else if (col < 96) m = (j >= 0);
      else               m = (j >= 0) && (j == p0 || j == p1);
      S[row * 132 + col] = m ? ((float)sc[p][r]) * 0.125f : -1e30f;
    }
  }
  __syncthreads();

  // softmax (row team = 16 lanes, 8 contiguous cols each) + P(bf16) write
  {
    int row = tid >> 4, q = tid & 15;
    float v[8];
    float mx = -3e38f;
#pragma unroll
    for (int e = 0; e < 8; ++e) {
      v[e] = S[row * 132 + 8 * q + e];
      mx = fmaxf(mx, v[e]);
    }
#pragma unroll
    for (int off = 1; off < 16; off <<= 1) mx = fmaxf(mx, __shfl_xor(mx, off, 64));
    float sum = 0.f;
#pragma unroll
    for (int e = 0; e < 8; ++e) {
      v[e] = __expf(v[e] - mx);
      sum += v[e];
    }
#pragma unroll
    for (int off = 1; off < 16; off <<= 1) sum += __shfl_xor(sum, off, 64);
    if (q == 0) rinv[row] = 1.0f / sum;
    uint4 pk = {pk2bf(v[0], v[1]), pk2bf(v[2], v[3]),
                pk2bf(v[4], v[5]), pk2bf(v[6], v[7])};
    *(uint4*)&P[row * 128 + ((q ^ (row & 7)) << 3)] = pk;
  }

  // Vt transpose-write, b64 along k: Vt[d] octet o holds cols [o^(d&7)^((d>>3)&7)]*8..+8
#pragma unroll
  for (int e = 0; e < 8; ++e) {
    int d = d0 + e;
    u32 lo = (u32)h16(vreg[0], e) | ((u32)h16(vreg[1], e) << 16);
    u32 hi = (u32)h16(vreg[2], e) | ((u32)h16(vreg[3], e) << 16);
    int oswz = (cq >> 1) ^ (d & 7) ^ ((d >> 3) & 7);
    uint2 pk2 = {lo, hi};
    *(uint2*)&Vt[d * 128 + oswz * 8 + (cq & 1) * 4] = pk2;
  }
  __syncthreads();

  // PV: wave wv owns d-tile wv. out 16x16 per wave.
  f32x4 oacc = {};
#pragma unroll
  for (int ks2 = 0; ks2 < 4; ++ks2) {
    int rowp = lane & 15;
    int chp = ks2 * 4 + (lane >> 4);
    bf16x8 pa = *(const bf16x8*)&P[rowp * 128 + ((chp ^ (rowp & 7)) << 3)];
    int dd = wv * 16 + (lane & 15);
    int swz = chp ^ (dd & 7) ^ ((dd >> 3) & 7);
    bf16x8 vb = *(const bf16x8*)&Vt[dd * 128 + swz * 8];
    oacc = __builtin_amdgcn_mfma_f32_16x16x32_bf16(pa, vb, oacc, 0, 0, 0);
  }
  {
    int dd = wv * 16 + (lane & 15);
#pragma unroll
    for (int r = 0; r < 4; ++r) {
      int row = (lane >> 4) * 4 + r;
      y[(size_t)(t0 + row) * NE + h * HD + dd] = f2bf(oacc[r] * rinv[row]);
    }
  }
}

extern "C" void kernel_launch(void* const* d_in, const int* in_sizes, int n_in,
                              void* d_out, int out_size, void* d_ws, size_t ws_size,
                              hipStream_t stream) {
  const float* x    = (const float*)d_in[0];
  const float* Wqkv = (const float*)d_in[1];
  const float* Wout = (const float*)d_in[2];
  const int*   nidx = (const int*)d_in[3];
  float* out = (float*)d_out;

  u16* ws16  = (u16*)d_ws;
  u16* xb    = ws16;                 // 2MB; reused as y after gemm1
  u16* WqkvT = ws16 + 1048576;       // 6MB
  u16* WoutT = ws16 + 4194304;       // 2MB
  float* Pg   = (float*)((char*)d_ws + (16u << 20));  // 2 x 12MB gemm1 partials
  float* Pout = (float*)((char*)d_ws + (40u << 20));  // 4 x 4MB gemm2 partials

  const int D = in_sizes[3] / (NH * TT);   // 83

  prep<<<2048, 256, 0, stream>>>(x, Wqkv, Wout, xb, WqkvT, WoutT);

  // qkv partials = x @ Wqkv, 128x128 tiles, split-K=2 -> 384 blocks
  gemm_bt<2, 128><<<dim3(24, 8, 2), 256, 0, stream>>>(xb, WqkvT, Pg, TT, 3 * NE, NE);

  // attention reads both partial slices directly (fused reduce); y overlays xb
  attn6<<<dim3(TT / 16, NH), 256, 0, stream>>>(Pg, nidx, xb, D);

  // out = y @ Wout, 128x128 tiles, split-K=4 -> 256 blocks, then reduce
  gemm_bt<4, 128><<<dim3(8, 8, 4), 256, 0, stream>>>(xb, WoutT, Pout, TT, NE, NE);
  reduce_out<<<TT * NE / 4 / 256, 256, 0, stream>>>(Pout, out);
}